// Round 21
// baseline (90.521 us; speedup 1.0000x reference)
//
#include <hip/hip_runtime.h>
#include <hip/hip_bf16.h>
#include <math.h>

// CausalFullAttention: out[b,l,h,d] = softmax_s( 0.125*(q.k + bias[l,s]), s<=l ) @ V
// B=4 L=S=2048 H=8 E=D=64, fp32 in/out, bf16 MFMA compute.
// R19 (resubmit after infra failure): staging VALU eliminated. Pre-pass converts
//      K->bf16 and V->bf16-transposed into ws; fa_part stages tiles with
//      global_load_lds (4 ops/thread, no cvt, no ds_write, no stage regs). K
//      row-perm rho + XOR e-slot swizzle baked into per-lane global addresses
//      (LDS linear). setprio around MFMA clusters (T5). qc<16 chunks normalize
//      in-kernel; merge covers only rows l>=1024.

typedef __bf16 bf16x8 __attribute__((ext_vector_type(8)));
typedef float  f32x4  __attribute__((ext_vector_type(4)));
typedef unsigned int u32;
typedef unsigned short u16;
typedef u32 u32x4 __attribute__((ext_vector_type(4)));

#define NB 4
#define NL 2048
#define NS 2048
#define NH 8
#define NE 64
#define ND 64

// ws layout (floats)
#define KBF_F 0                    // 2,097,152 floats = 4.19M bf16
#define VT_F  2097152              // 2,097,152 floats = 4.19M bf16 (transposed V)
#define OP_F  4194304              // 2 slots x 2,097,152 floats (half-L partial O)
#define M_F   8388608              // 2 slots x 32,768
#define L_F   8454144              // 2 slots x 32,768
#define WS_NEED_F 8519680          // 34,078,720 bytes

typedef __attribute__((address_space(3))) u32 lds_u32;
typedef __attribute__((address_space(1))) const u32 glb_u32;
__device__ __forceinline__ void gload16(const void* g, void* l) {
    __builtin_amdgcn_global_load_lds((glb_u32*)g, (lds_u32*)l, 16, 0, 0);
}

__device__ __forceinline__ u32 cvtpk(float lo, float hi) {
    u32 r;
    asm("v_cvt_pk_bf16_f32 %0, %1, %2" : "=v"(r) : "v"(lo), "v"(hi));
    return r;
}
__device__ __forceinline__ float bpermf(int srclane, float v) {
    return __uint_as_float((u32)__builtin_amdgcn_ds_bpermute(srclane << 2, (int)__float_as_uint(v)));
}
__device__ __forceinline__ bf16x8 cvt8s(f32x4 a, f32x4 b, float sc) {
    bf16x8 r;
    r[0]=(__bf16)(a[0]*sc); r[1]=(__bf16)(a[1]*sc); r[2]=(__bf16)(a[2]*sc); r[3]=(__bf16)(a[3]*sc);
    r[4]=(__bf16)(b[0]*sc); r[5]=(__bf16)(b[1]*sc); r[6]=(__bf16)(b[2]*sc); r[7]=(__bf16)(b[3]*sc);
    return r;
}
__device__ __forceinline__ bf16x8 cvt8(f32x4 a, f32x4 b) {
    bf16x8 r;
    r[0]=(__bf16)a[0]; r[1]=(__bf16)a[1]; r[2]=(__bf16)a[2]; r[3]=(__bf16)a[3];
    r[4]=(__bf16)b[0]; r[5]=(__bf16)b[1]; r[6]=(__bf16)b[2]; r[7]=(__bf16)b[3];
    return r;
}

// ---------------- pre-pass 1: K (fp32) -> Kbf (bf16), same layout ----------------
__global__ __launch_bounds__(256)
void cvt_k(const float* __restrict__ K, u16* __restrict__ Kbf)
{
    const int i = (blockIdx.x * 256 + threadIdx.x) * 8;
    f32x4 a = *(const f32x4*)(K + i);
    f32x4 b = *(const f32x4*)(K + i + 4);
    *(bf16x8*)(Kbf + i) = cvt8(a, b);
}

// ------------- pre-pass 2: V [b][s][h][d] fp32 -> Vt [b][h][d][s] bf16 -----------
__global__ __launch_bounds__(256)
void trans_v(const float* __restrict__ V, u16* __restrict__ Vt)
{
    __shared__ __bf16 T[64][72];
    const int id = blockIdx.x;
    const int bh = id >> 5, sblk = (id & 31) << 6;
    const int b = bh >> 3, h = bh & 7;
    const int t = threadIdx.x;
    {
        const int sl = t >> 2, d0 = (t & 3) << 4;
        const float* vp = V + (((size_t)(b * NS + sblk + sl)) * NH + h) * ND + d0;
        f32x4 a0 = ((const f32x4*)vp)[0], a1 = ((const f32x4*)vp)[1];
        f32x4 a2 = ((const f32x4*)vp)[2], a3 = ((const f32x4*)vp)[3];
        *(bf16x8*)&T[sl][d0]     = cvt8(a0, a1);
        *(bf16x8*)&T[sl][d0 + 8] = cvt8(a2, a3);
    }
    __syncthreads();
    {
        const int dl = t >> 2, s0 = (t & 3) << 4;
        bf16x8 o0, o1;
        #pragma unroll
        for (int k = 0; k < 8; ++k) { o0[k] = T[s0 + k][dl]; o1[k] = T[s0 + 8 + k][dl]; }
        u16* op = Vt + (((size_t)(b * NH + h)) * ND + dl) * NS + sblk + s0;
        *(bf16x8*)op       = o0;
        *(bf16x8*)(op + 8) = o1;
    }
}

// ---- core: 256 threads, 4 waves x 16 q-rows, tiles [t0,t1); gload_lds staging ----
template<bool WRITE_WS>
__device__ __forceinline__ void fa_core(const float* __restrict__ Q,
                                        const u16* __restrict__ Kbf,
                                        const u16* __restrict__ Vt,
                                        const float* __restrict__ Bias,
                                        float* __restrict__ OutOrO,
                                        float* __restrict__ Mp, float* __restrict__ Lp,
                                        int b, int h, int qb, int t0, int t1)
{
    __shared__ __bf16 Klin[2][4096];   // 64 rows x 64 bf16; row r = rho(kv), e-slot XOR r&7
    __shared__ __bf16 Vlin[2][4096];   // 64 rows (d) x 64 bf16; kv-slot XOR sd(d)

    const int tid  = threadIdx.x;
    const int w    = tid >> 6, lane = tid & 63;
    const int g    = lane >> 4, li = lane & 15;
    const int qw   = qb + (w << 4);

    const float SC = 0.125f * 1.44269504088896340736f;

    bf16x8 qa[2];
    {
        const float* qp = Q + (((size_t)(b * NL + qw + li)) * NH + h) * NE;
        #pragma unroll
        for (int eh = 0; eh < 2; ++eh) {
            const int e0 = eh * 32 + g * 8;
            f32x4 f0 = *(const f32x4*)(qp + e0);
            f32x4 f1 = *(const f32x4*)(qp + e0 + 4);
            qa[eh] = cvt8s(f0, f1, SC);
        }
    }

    f32x4 o[4] = {};
    float m_run = -INFINITY, l_run = 0.0f;

    const int nt = t1 - t0;

    // per-lane gload source geometry (2 K issues + 2 V issues per thread-wave)
    const int ob0 = w * 2048 + lane * 16;          // LDS byte offset, issue 0
    const int r0  = ob0 >> 7,        j0 = (ob0 >> 4) & 7;
    const int r1  = (ob0 + 1024) >> 7, j1 = ((ob0 + 1024) >> 4) & 7;
    // rho^-1: kv2=r4, kv4:3=r3:2, rest pass-through
    const int kv0i = (r0 & 0x23) | ((r0 & 0x10) >> 2) | ((r0 & 0x0C) << 1);
    const int kv1i = (r1 & 0x23) | ((r1 & 0x10) >> 2) | ((r1 & 0x0C) << 1);
    const u16* kgp0 = Kbf + ((size_t)(b * NS + kv0i) * NH + h) * NE + (j0 ^ (r0 & 7)) * 8;
    const u16* kgp1 = Kbf + ((size_t)(b * NS + kv1i) * NH + h) * NE + (j1 ^ (r1 & 7)) * 8;
    const int sd0 = (r0 ^ (r0 >> 3)) & 7, sd1 = (r1 ^ (r1 >> 3)) & 7;
    const u16* vgp0 = Vt + ((size_t)(b * NH + h) * ND + r0) * NS + (j0 ^ sd0) * 8;
    const u16* vgp1 = Vt + ((size_t)(b * NH + h) * ND + r1) * NS + (j1 ^ sd1) * 8;

    const float* bp0 = Bias + (size_t)(qw + li) * NS + g * 8;

    f32x4 bc[4], bn[4];

    auto stage = [&](int buf, int T) {
        const size_t kq = (size_t)(T << 6) * (NH * NE);
        const int    vq = T << 6;
        gload16(kgp0 + kq, &Klin[buf][w * 1024]);
        gload16(kgp1 + kq, &Klin[buf][w * 1024 + 512]);
        gload16(vgp0 + vq, &Vlin[buf][w * 1024]);
        gload16(vgp1 + vq, &Vlin[buf][w * 1024 + 512]);
    };
    auto load_bias = [&](f32x4 (&bx)[4], int T) {
        const float* bp = bp0 + (T << 6);
        #pragma unroll
        for (int c = 0; c < 4; ++c)
            bx[c] = *(const f32x4*)(bp + ((c >> 1) << 5) + ((c & 1) << 2));
    };

    // prologue
    stage(0, t0);
    load_bias(bc, t0);
    __syncthreads();

    for (int i = 0; i < nt; ++i) {
        const int t = t0 + i;
        const int cur = i & 1;
        const bool more = (i + 1 < nt);

        if (more) { stage(cur ^ 1, t + 1); load_bias(bn, t + 1); }

        const int kv0 = t << 6;
        if (kv0 <= qw + 15) {
            // swapped QK^T: s[c][r] = S[kv=kv0+32(c>>1)+8g+4(c&1)+r][q=qw+li]
            f32x4 s[4];
            __builtin_amdgcn_s_setprio(1);
            #pragma unroll
            for (int c = 0; c < 4; ++c) {
                f32x4 acc = {};
                #pragma unroll
                for (int eh = 0; eh < 2; ++eh) {
                    bf16x8 kb = *(const bf16x8*)&Klin[cur][(c * 16 + li) * 64 + (((eh * 4 + g) ^ (li & 7)) * 8)];
                    acc = __builtin_amdgcn_mfma_f32_16x16x32_bf16(kb, qa[eh], acc, 0, 0, 0);
                }
                s[c] = acc;
            }
            __builtin_amdgcn_s_setprio(0);
            const int lg = qw + li;
            if (kv0 + 63 > qw) {
                #pragma unroll
                for (int c = 0; c < 4; ++c) {
                    const int kvb = kv0 + ((c >> 1) << 5) + (g << 3) + ((c & 1) << 2);
                    #pragma unroll
                    for (int r = 0; r < 4; ++r)
                        s[c][r] = (kvb + r <= lg) ? fmaf(bc[c][r], SC, s[c][r]) : -INFINITY;
                }
            } else {
                #pragma unroll
                for (int c = 0; c < 4; ++c)
                    #pragma unroll
                    for (int r = 0; r < 4; ++r)
                        s[c][r] = fmaf(bc[c][r], SC, s[c][r]);
            }
            float pm = fmaxf(
                fmaxf(fmaxf(fmaxf(s[0][0],s[0][1]),fmaxf(s[0][2],s[0][3])),
                      fmaxf(fmaxf(s[1][0],s[1][1]),fmaxf(s[1][2],s[1][3]))),
                fmaxf(fmaxf(fmaxf(s[2][0],s[2][1]),fmaxf(s[2][2],s[2][3])),
                      fmaxf(fmaxf(s[3][0],s[3][1]),fmaxf(s[3][2],s[3][3]))));
            pm = fmaxf(pm, __shfl_xor(pm, 16, 64));
            pm = fmaxf(pm, __shfl_xor(pm, 32, 64));
            if (!__all(pm <= m_run + 8.0f)) {     // defer-max
                const float mn = fmaxf(m_run, pm);
                const float corr = exp2f(m_run - mn);
                m_run = mn; l_run *= corr;
                #pragma unroll
                for (int j = 0; j < 4; ++j) {
                    const float cj = bpermf(g * 20 + j, corr);
                    o[0][j] *= cj; o[1][j] *= cj; o[2][j] *= cj; o[3][j] *= cj;
                }
            }
            #pragma unroll
            for (int c = 0; c < 4; ++c)
                #pragma unroll
                for (int r = 0; r < 4; ++r)
                    s[c][r] = exp2f(s[c][r] - m_run);
            float rs = ((s[0][0]+s[0][1])+(s[0][2]+s[0][3]))
                     + ((s[1][0]+s[1][1])+(s[1][2]+s[1][3]))
                     + ((s[2][0]+s[2][1])+(s[2][2]+s[2][3]))
                     + ((s[3][0]+s[3][1])+(s[3][2]+s[3][3]));
            rs += __shfl_xor(rs, 16, 64);
            rs += __shfl_xor(rs, 32, 64);
            l_run += rs;
            u32x4 pw0, pw1;
            pw0[0] = cvtpk(s[0][0], s[0][1]); pw0[1] = cvtpk(s[0][2], s[0][3]);
            pw0[2] = cvtpk(s[1][0], s[1][1]); pw0[3] = cvtpk(s[1][2], s[1][3]);
            pw1[0] = cvtpk(s[2][0], s[2][1]); pw1[1] = cvtpk(s[2][2], s[2][3]);
            pw1[2] = cvtpk(s[3][0], s[3][1]); pw1[3] = cvtpk(s[3][2], s[3][3]);
            const bf16x8 pa0 = __builtin_bit_cast(bf16x8, pw0);
            const bf16x8 pa1 = __builtin_bit_cast(bf16x8, pw1);
            __builtin_amdgcn_s_setprio(1);
            #pragma unroll
            for (int dt = 0; dt < 4; ++dt) {
                const int d = dt * 16 + li;
                const int sd = (d ^ (d >> 3)) & 7;
                bf16x8 v0 = *(const bf16x8*)&Vlin[cur][d * 64 + ((g ^ sd) * 8)];
                bf16x8 v1 = *(const bf16x8*)&Vlin[cur][d * 64 + (((4 + g) ^ sd) * 8)];
                o[dt] = __builtin_amdgcn_mfma_f32_16x16x32_bf16(pa0, v0, o[dt], 0, 0, 0);
                o[dt] = __builtin_amdgcn_mfma_f32_16x16x32_bf16(pa1, v1, o[dt], 0, 0, 0);
            }
            __builtin_amdgcn_s_setprio(0);
        }

        if (more) {
            __syncthreads();    // drains gloads for t+1, separates buffer reuse
            #pragma unroll
            for (int c = 0; c < 4; ++c) bc[c] = bn[c];
        }
    }

    if (WRITE_WS) {
        #pragma unroll
        for (int j = 0; j < 4; ++j) {
            const int lp = qw + g * 4 + j - 1024;   // half-L index
            float* op = OutOrO + (((size_t)(b * 1024 + lp)) * NH + h) * ND + li;
            op[0]  = o[0][j];
            op[16] = o[1][j];
            op[32] = o[2][j];
            op[48] = o[3][j];
        }
        if (g == 0) {
            const size_t rh = ((size_t)(b * 1024 + qw + li - 1024)) * NH + h;
            Mp[rh] = m_run;
            Lp[rh] = l_run;
        }
    } else {
        #pragma unroll
        for (int j = 0; j < 4; ++j) {
            const float lj = bpermf(g * 20 + j, l_run);
            const float inv = 1.0f / lj;
            const int lgq = qw + g * 4 + j;
            float* op = OutOrO + (((size_t)(b * NL + lgq)) * NH + h) * ND + li;
            op[0]  = o[0][j] * inv;
            op[16] = o[1][j] * inv;
            op[32] = o[2][j] * inv;
            op[48] = o[3][j] * inv;
        }
    }
}

// ---- split kernel: 1536 blocks = 48 segs (heavy-first-ish) x 32 bh ----
__global__ __launch_bounds__(256)
void fa_part(const float* __restrict__ Q, const float* __restrict__ Bias,
             float* __restrict__ Ws, float* __restrict__ Out)
{
    const int id = blockIdx.x;
    const int bh = id & 31, k = id >> 5;
    const int b  = bh >> 3, h = bh & 7;
    int qc, s;
    if (k < 16)      { qc = 31 - k;        s = 0; }
    else if (k < 32) { qc = 31 - (k - 16); s = 1; }
    else             { qc = 47 - k;        s = 0; }
    const int qb = qc << 6;
    const int t0 = s ? 16 : 0;
    const int t1 = s ? (qc + 1) : (qc < 16 ? qc + 1 : 16);

    const u16* Kbf = (const u16*)(Ws + KBF_F);
    const u16* Vt  = (const u16*)(Ws + VT_F);
    if (qc >= 16) {
        float* Op = Ws + OP_F + (size_t)s * 2097152;
        float* Mp = Ws + M_F + (size_t)s * 32768;
        float* Lp = Ws + L_F + (size_t)s * 32768;
        fa_core<true>(Q, Kbf, Vt, Bias, Op, Mp, Lp, b, h, qb, t0, t1);
    } else {
        fa_core<false>(Q, Kbf, Vt, Bias, Out, nullptr, nullptr, b, h, qb, t0, t1);
    }
}

// ---- merge kernel: rows l in [1024,2048) only (always exactly 2 segments) ----
__global__ __launch_bounds__(256)
void fa_merge(const float* __restrict__ Ws, float* __restrict__ Out)
{
    const int gid  = blockIdx.x * 256 + threadIdx.x;   // 0 .. 2,097,152/4 - 1
    const int base = gid << 2;
    const int rh   = base >> 6;                        // (b*1024+l')*NH+h
    const int d0   = base & 63;
    const float* O1 = Ws + OP_F;
    const float* O2 = Ws + OP_F + 2097152;
    const float m1 = Ws[M_F + rh],         l1 = Ws[L_F + rh];
    const float m2 = Ws[M_F + 32768 + rh], l2 = Ws[L_F + 32768 + rh];
    const float mm = fmaxf(m1, m2);
    const float c1 = exp2f(m1 - mm), c2 = exp2f(m2 - mm);
    const float inv = 1.0f / (c1 * l1 + c2 * l2);
    const f32x4 o1 = *(const f32x4*)(O1 + base);
    const f32x4 o2 = *(const f32x4*)(O2 + base);
    f32x4 r;
    #pragma unroll
    for (int e = 0; e < 4; ++e) r[e] = (c1 * o1[e] + c2 * o2[e]) * inv;
    const int h  = rh & 7;
    const int bl = rh >> 3;
    const int lp = bl & 1023, b = bl >> 10;
    float* op = Out + (((size_t)(b * NL + 1024 + lp)) * NH + h) * ND + d0;
    *(f32x4*)op = r;
}

// ---- fallback (ws only fits Kbf+Vt): single kernel, full chunk ranges ----
__global__ __launch_bounds__(256)
void fa_single(const float* __restrict__ Q, const float* __restrict__ Bias,
               float* __restrict__ Ws, float* __restrict__ Out)
{
    const int id = blockIdx.x;
    const int bh = id & 31, qc = 31 - (id >> 5);
    const int b  = bh >> 3, h = bh & 7;
    const u16* Kbf = (const u16*)(Ws + KBF_F);
    const u16* Vt  = (const u16*)(Ws + VT_F);
    fa_core<false>(Q, Kbf, Vt, Bias, Out, nullptr, nullptr, b, h, qc << 6, 0, qc + 1);
}

extern "C" void kernel_launch(void* const* d_in, const int* in_sizes, int n_in,
                              void* d_out, int out_size, void* d_ws, size_t ws_size,
                              hipStream_t stream)
{
    const float* Q    = (const float*)d_in[0];
    const float* K    = (const float*)d_in[1];
    const float* V    = (const float*)d_in[2];
    const float* Bias = (const float*)d_in[3];
    float* Out = (float*)d_out;
    float* Ws  = (float*)d_ws;

    // pre-passes: K -> bf16 (same layout), V -> bf16 transposed [b][h][d][s]
    cvt_k  <<<dim3(2048), dim3(256), 0, stream>>>(K, (u16*)(Ws + KBF_F));
    trans_v<<<dim3(1024), dim3(256), 0, stream>>>(V, (u16*)(Ws + VT_F));

    if (ws_size >= (size_t)WS_NEED_F * sizeof(float)) {
        fa_part <<<dim3(1536), dim3(256), 0, stream>>>(Q, Bias, Ws, Out);
        fa_merge<<<dim3(2048), dim3(256), 0, stream>>>(Ws, Out);
    } else {
        fa_single<<<dim3(1024), dim3(256), 0, stream>>>(Q, Bias, Ws, Out);
    }
}

// Round 22
// 88.735 us; speedup vs baseline: 1.0201x; 1.0201x over previous
//
#include <hip/hip_runtime.h>
#include <hip/hip_bf16.h>
#include <math.h>

// CausalFullAttention: out[b,l,h,d] = softmax_s( 0.125*(q.k + bias[l,s]), s<=l ) @ V
// B=4 L=S=2048 H=8 E=D=64, fp32 in/out, bf16 MFMA compute.
// R21: R19 + (1) LDS hoisted to kernel scope (single 32KB alloc -> 4 blocks/CU;
//      R19's dual template instantiation silently doubled LDS to 64KB), and
//      (2) cvt_k+trans_v fused into one prep kernel (one launch+drain less).
//      Core (gload_lds staging, K row-perm + XOR swizzles, setprio) unchanged.

typedef __bf16 bf16x8 __attribute__((ext_vector_type(8)));
typedef float  f32x4  __attribute__((ext_vector_type(4)));
typedef unsigned int u32;
typedef unsigned short u16;
typedef u32 u32x4 __attribute__((ext_vector_type(4)));

#define NB 4
#define NL 2048
#define NS 2048
#define NH 8
#define NE 64
#define ND 64

// ws layout (floats)
#define KBF_F 0                    // 2,097,152 floats = 4.19M bf16
#define VT_F  2097152              // 2,097,152 floats = 4.19M bf16 (transposed V)
#define OP_F  4194304              // 2 slots x 2,097,152 floats (half-L partial O)
#define M_F   8388608              // 2 slots x 32,768
#define L_F   8454144              // 2 slots x 32,768
#define WS_NEED_F 8519680          // 34,078,720 bytes

typedef __attribute__((address_space(3))) u32 lds_u32;
typedef __attribute__((address_space(1))) const u32 glb_u32;
__device__ __forceinline__ void gload16(const void* g, void* l) {
    __builtin_amdgcn_global_load_lds((glb_u32*)g, (lds_u32*)l, 16, 0, 0);
}

__device__ __forceinline__ u32 cvtpk(float lo, float hi) {
    u32 r;
    asm("v_cvt_pk_bf16_f32 %0, %1, %2" : "=v"(r) : "v"(lo), "v"(hi));
    return r;
}
__device__ __forceinline__ float bpermf(int srclane, float v) {
    return __uint_as_float((u32)__builtin_amdgcn_ds_bpermute(srclane << 2, (int)__float_as_uint(v)));
}
__device__ __forceinline__ bf16x8 cvt8s(f32x4 a, f32x4 b, float sc) {
    bf16x8 r;
    r[0]=(__bf16)(a[0]*sc); r[1]=(__bf16)(a[1]*sc); r[2]=(__bf16)(a[2]*sc); r[3]=(__bf16)(a[3]*sc);
    r[4]=(__bf16)(b[0]*sc); r[5]=(__bf16)(b[1]*sc); r[6]=(__bf16)(b[2]*sc); r[7]=(__bf16)(b[3]*sc);
    return r;
}
__device__ __forceinline__ bf16x8 cvt8(f32x4 a, f32x4 b) {
    bf16x8 r;
    r[0]=(__bf16)a[0]; r[1]=(__bf16)a[1]; r[2]=(__bf16)a[2]; r[3]=(__bf16)a[3];
    r[4]=(__bf16)b[0]; r[5]=(__bf16)b[1]; r[6]=(__bf16)b[2]; r[7]=(__bf16)b[3];
    return r;
}

// -------- fused pre-pass: blocks [0,2048) convert K; [2048,3072) transpose V -----
__global__ __launch_bounds__(256)
void prep(const float* __restrict__ K, const float* __restrict__ V,
          u16* __restrict__ Kbf, u16* __restrict__ Vt)
{
    __shared__ __bf16 T[64][72];
    const int bid = blockIdx.x;
    const int t   = threadIdx.x;
    if (bid < 2048) {
        const int i = (bid * 256 + t) * 8;
        f32x4 a = *(const f32x4*)(K + i);
        f32x4 b = *(const f32x4*)(K + i + 4);
        *(bf16x8*)(Kbf + i) = cvt8(a, b);
    } else {
        const int id = bid - 2048;
        const int bh = id >> 5, sblk = (id & 31) << 6;
        const int b = bh >> 3, h = bh & 7;
        {
            const int sl = t >> 2, d0 = (t & 3) << 4;
            const float* vp = V + (((size_t)(b * NS + sblk + sl)) * NH + h) * ND + d0;
            f32x4 a0 = ((const f32x4*)vp)[0], a1 = ((const f32x4*)vp)[1];
            f32x4 a2 = ((const f32x4*)vp)[2], a3 = ((const f32x4*)vp)[3];
            *(bf16x8*)&T[sl][d0]     = cvt8(a0, a1);
            *(bf16x8*)&T[sl][d0 + 8] = cvt8(a2, a3);
        }
        __syncthreads();
        {
            const int dl = t >> 2, s0 = (t & 3) << 4;
            bf16x8 o0, o1;
            #pragma unroll
            for (int k = 0; k < 8; ++k) { o0[k] = T[s0 + k][dl]; o1[k] = T[s0 + 8 + k][dl]; }
            u16* op = Vt + (((size_t)(b * NH + h)) * ND + dl) * NS + sblk + s0;
            *(bf16x8*)op       = o0;
            *(bf16x8*)(op + 8) = o1;
        }
    }
}

// ---- core: 256 threads, 4 waves x 16 q-rows, tiles [t0,t1); gload_lds staging ----
// LDS buffers passed in from kernel scope (single allocation).
template<bool WRITE_WS>
__device__ __forceinline__ void fa_core(const float* __restrict__ Q,
                                        const u16* __restrict__ Kbf,
                                        const u16* __restrict__ Vt,
                                        const float* __restrict__ Bias,
                                        float* __restrict__ OutOrO,
                                        float* __restrict__ Mp, float* __restrict__ Lp,
                                        int b, int h, int qb, int t0, int t1,
                                        __bf16 (*Klin)[4096], __bf16 (*Vlin)[4096])
{
    const int tid  = threadIdx.x;
    const int w    = tid >> 6, lane = tid & 63;
    const int g    = lane >> 4, li = lane & 15;
    const int qw   = qb + (w << 4);

    const float SC = 0.125f * 1.44269504088896340736f;

    bf16x8 qa[2];
    {
        const float* qp = Q + (((size_t)(b * NL + qw + li)) * NH + h) * NE;
        #pragma unroll
        for (int eh = 0; eh < 2; ++eh) {
            const int e0 = eh * 32 + g * 8;
            f32x4 f0 = *(const f32x4*)(qp + e0);
            f32x4 f1 = *(const f32x4*)(qp + e0 + 4);
            qa[eh] = cvt8s(f0, f1, SC);
        }
    }

    f32x4 o[4] = {};
    float m_run = -INFINITY, l_run = 0.0f;

    const int nt = t1 - t0;

    // per-lane gload source geometry (2 K issues + 2 V issues per thread)
    const int ob0 = w * 2048 + lane * 16;            // LDS byte offset, issue 0
    const int r0  = ob0 >> 7,          j0 = (ob0 >> 4) & 7;
    const int r1  = (ob0 + 1024) >> 7, j1 = ((ob0 + 1024) >> 4) & 7;
    // rho^-1: kv2=r4, kv4:3=r3:2, rest pass-through
    const int kv0i = (r0 & 0x23) | ((r0 & 0x10) >> 2) | ((r0 & 0x0C) << 1);
    const int kv1i = (r1 & 0x23) | ((r1 & 0x10) >> 2) | ((r1 & 0x0C) << 1);
    const u16* kgp0 = Kbf + ((size_t)(b * NS + kv0i) * NH + h) * NE + (j0 ^ (r0 & 7)) * 8;
    const u16* kgp1 = Kbf + ((size_t)(b * NS + kv1i) * NH + h) * NE + (j1 ^ (r1 & 7)) * 8;
    const int sd0 = (r0 ^ (r0 >> 3)) & 7, sd1 = (r1 ^ (r1 >> 3)) & 7;
    const u16* vgp0 = Vt + ((size_t)(b * NH + h) * ND + r0) * NS + (j0 ^ sd0) * 8;
    const u16* vgp1 = Vt + ((size_t)(b * NH + h) * ND + r1) * NS + (j1 ^ sd1) * 8;

    const float* bp0 = Bias + (size_t)(qw + li) * NS + g * 8;

    f32x4 bc[4], bn[4];

    auto stage = [&](int buf, int T) {
        const size_t kq = (size_t)(T << 6) * (NH * NE);
        const int    vq = T << 6;
        gload16(kgp0 + kq, &Klin[buf][w * 1024]);
        gload16(kgp1 + kq, &Klin[buf][w * 1024 + 512]);
        gload16(vgp0 + vq, &Vlin[buf][w * 1024]);
        gload16(vgp1 + vq, &Vlin[buf][w * 1024 + 512]);
    };
    auto load_bias = [&](f32x4 (&bx)[4], int T) {
        const float* bp = bp0 + (T << 6);
        #pragma unroll
        for (int c = 0; c < 4; ++c)
            bx[c] = *(const f32x4*)(bp + ((c >> 1) << 5) + ((c & 1) << 2));
    };

    // prologue
    stage(0, t0);
    load_bias(bc, t0);
    __syncthreads();

    for (int i = 0; i < nt; ++i) {
        const int t = t0 + i;
        const int cur = i & 1;
        const bool more = (i + 1 < nt);

        if (more) { stage(cur ^ 1, t + 1); load_bias(bn, t + 1); }

        const int kv0 = t << 6;
        if (kv0 <= qw + 15) {
            // swapped QK^T: s[c][r] = S[kv=kv0+32(c>>1)+8g+4(c&1)+r][q=qw+li]
            f32x4 s[4];
            __builtin_amdgcn_s_setprio(1);
            #pragma unroll
            for (int c = 0; c < 4; ++c) {
                f32x4 acc = {};
                #pragma unroll
                for (int eh = 0; eh < 2; ++eh) {
                    bf16x8 kb = *(const bf16x8*)&Klin[cur][(c * 16 + li) * 64 + (((eh * 4 + g) ^ (li & 7)) * 8)];
                    acc = __builtin_amdgcn_mfma_f32_16x16x32_bf16(kb, qa[eh], acc, 0, 0, 0);
                }
                s[c] = acc;
            }
            __builtin_amdgcn_s_setprio(0);
            const int lg = qw + li;
            if (kv0 + 63 > qw) {
                #pragma unroll
                for (int c = 0; c < 4; ++c) {
                    const int kvb = kv0 + ((c >> 1) << 5) + (g << 3) + ((c & 1) << 2);
                    #pragma unroll
                    for (int r = 0; r < 4; ++r)
                        s[c][r] = (kvb + r <= lg) ? fmaf(bc[c][r], SC, s[c][r]) : -INFINITY;
                }
            } else {
                #pragma unroll
                for (int c = 0; c < 4; ++c)
                    #pragma unroll
                    for (int r = 0; r < 4; ++r)
                        s[c][r] = fmaf(bc[c][r], SC, s[c][r]);
            }
            float pm = fmaxf(
                fmaxf(fmaxf(fmaxf(s[0][0],s[0][1]),fmaxf(s[0][2],s[0][3])),
                      fmaxf(fmaxf(s[1][0],s[1][1]),fmaxf(s[1][2],s[1][3]))),
                fmaxf(fmaxf(fmaxf(s[2][0],s[2][1]),fmaxf(s[2][2],s[2][3])),
                      fmaxf(fmaxf(s[3][0],s[3][1]),fmaxf(s[3][2],s[3][3]))));
            pm = fmaxf(pm, __shfl_xor(pm, 16, 64));
            pm = fmaxf(pm, __shfl_xor(pm, 32, 64));
            if (!__all(pm <= m_run + 8.0f)) {     // defer-max
                const float mn = fmaxf(m_run, pm);
                const float corr = exp2f(m_run - mn);
                m_run = mn; l_run *= corr;
                #pragma unroll
                for (int j = 0; j < 4; ++j) {
                    const float cj = bpermf(g * 20 + j, corr);
                    o[0][j] *= cj; o[1][j] *= cj; o[2][j] *= cj; o[3][j] *= cj;
                }
            }
            #pragma unroll
            for (int c = 0; c < 4; ++c)
                #pragma unroll
                for (int r = 0; r < 4; ++r)
                    s[c][r] = exp2f(s[c][r] - m_run);
            float rs = ((s[0][0]+s[0][1])+(s[0][2]+s[0][3]))
                     + ((s[1][0]+s[1][1])+(s[1][2]+s[1][3]))
                     + ((s[2][0]+s[2][1])+(s[2][2]+s[2][3]))
                     + ((s[3][0]+s[3][1])+(s[3][2]+s[3][3]));
            rs += __shfl_xor(rs, 16, 64);
            rs += __shfl_xor(rs, 32, 64);
            l_run += rs;
            u32x4 pw0, pw1;
            pw0[0] = cvtpk(s[0][0], s[0][1]); pw0[1] = cvtpk(s[0][2], s[0][3]);
            pw0[2] = cvtpk(s[1][0], s[1][1]); pw0[3] = cvtpk(s[1][2], s[1][3]);
            pw1[0] = cvtpk(s[2][0], s[2][1]); pw1[1] = cvtpk(s[2][2], s[2][3]);
            pw1[2] = cvtpk(s[3][0], s[3][1]); pw1[3] = cvtpk(s[3][2], s[3][3]);
            const bf16x8 pa0 = __builtin_bit_cast(bf16x8, pw0);
            const bf16x8 pa1 = __builtin_bit_cast(bf16x8, pw1);
            __builtin_amdgcn_s_setprio(1);
            #pragma unroll
            for (int dt = 0; dt < 4; ++dt) {
                const int d = dt * 16 + li;
                const int sd = (d ^ (d >> 3)) & 7;
                bf16x8 v0 = *(const bf16x8*)&Vlin[cur][d * 64 + ((g ^ sd) * 8)];
                bf16x8 v1 = *(const bf16x8*)&Vlin[cur][d * 64 + (((4 + g) ^ sd) * 8)];
                o[dt] = __builtin_amdgcn_mfma_f32_16x16x32_bf16(pa0, v0, o[dt], 0, 0, 0);
                o[dt] = __builtin_amdgcn_mfma_f32_16x16x32_bf16(pa1, v1, o[dt], 0, 0, 0);
            }
            __builtin_amdgcn_s_setprio(0);
        }

        if (more) {
            __syncthreads();    // drains gloads for t+1, separates buffer reuse
            #pragma unroll
            for (int c = 0; c < 4; ++c) bc[c] = bn[c];
        }
    }

    if (WRITE_WS) {
        #pragma unroll
        for (int j = 0; j < 4; ++j) {
            const int lp = qw + g * 4 + j - 1024;   // half-L index
            float* op = OutOrO + (((size_t)(b * 1024 + lp)) * NH + h) * ND + li;
            op[0]  = o[0][j];
            op[16] = o[1][j];
            op[32] = o[2][j];
            op[48] = o[3][j];
        }
        if (g == 0) {
            const size_t rh = ((size_t)(b * 1024 + qw + li - 1024)) * NH + h;
            Mp[rh] = m_run;
            Lp[rh] = l_run;
        }
    } else {
        #pragma unroll
        for (int j = 0; j < 4; ++j) {
            const float lj = bpermf(g * 20 + j, l_run);
            const float inv = 1.0f / lj;
            const int lgq = qw + g * 4 + j;
            float* op = OutOrO + (((size_t)(b * NL + lgq)) * NH + h) * ND + li;
            op[0]  = o[0][j] * inv;
            op[16] = o[1][j] * inv;
            op[32] = o[2][j] * inv;
            op[48] = o[3][j] * inv;
        }
    }
}

// ---- split kernel: 1536 blocks = 48 segs (heavy-first-ish) x 32 bh ----
__global__ __launch_bounds__(256)
void fa_part(const float* __restrict__ Q, const float* __restrict__ Bias,
             float* __restrict__ Ws, float* __restrict__ Out)
{
    __shared__ __bf16 Klin[2][4096];   // single allocation, shared by both paths
    __shared__ __bf16 Vlin[2][4096];

    const int id = blockIdx.x;
    const int bh = id & 31, k = id >> 5;
    const int b  = bh >> 3, h = bh & 7;
    int qc, s;
    if (k < 16)      { qc = 31 - k;        s = 0; }
    else if (k < 32) { qc = 31 - (k - 16); s = 1; }
    else             { qc = 47 - k;        s = 0; }
    const int qb = qc << 6;
    const int t0 = s ? 16 : 0;
    const int t1 = s ? (qc + 1) : (qc < 16 ? qc + 1 : 16);

    const u16* Kbf = (const u16*)(Ws + KBF_F);
    const u16* Vt  = (const u16*)(Ws + VT_F);
    if (qc >= 16) {
        float* Op = Ws + OP_F + (size_t)s * 2097152;
        float* Mp = Ws + M_F + (size_t)s * 32768;
        float* Lp = Ws + L_F + (size_t)s * 32768;
        fa_core<true>(Q, Kbf, Vt, Bias, Op, Mp, Lp, b, h, qb, t0, t1, Klin, Vlin);
    } else {
        fa_core<false>(Q, Kbf, Vt, Bias, Out, nullptr, nullptr, b, h, qb, t0, t1, Klin, Vlin);
    }
}

// ---- merge kernel: rows l in [1024,2048) only (always exactly 2 segments) ----
__global__ __launch_bounds__(256)
void fa_merge(const float* __restrict__ Ws, float* __restrict__ Out)
{
    const int gid  = blockIdx.x * 256 + threadIdx.x;   // 0 .. 2,097,152/4 - 1
    const int base = gid << 2;
    const int rh   = base >> 6;                        // (b*1024+l')*NH+h
    const int d0   = base & 63;
    const float* O1 = Ws + OP_F;
    const float* O2 = Ws + OP_F + 2097152;
    const float m1 = Ws[M_F + rh],         l1 = Ws[L_F + rh];
    const float m2 = Ws[M_F + 32768 + rh], l2 = Ws[L_F + 32768 + rh];
    const float mm = fmaxf(m1, m2);
    const float c1 = exp2f(m1 - mm), c2 = exp2f(m2 - mm);
    const float inv = 1.0f / (c1 * l1 + c2 * l2);
    const f32x4 o1 = *(const f32x4*)(O1 + base);
    const f32x4 o2 = *(const f32x4*)(O2 + base);
    f32x4 r;
    #pragma unroll
    for (int e = 0; e < 4; ++e) r[e] = (c1 * o1[e] + c2 * o2[e]) * inv;
    const int h  = rh & 7;
    const int bl = rh >> 3;
    const int lp = bl & 1023, b = bl >> 10;
    float* op = Out + (((size_t)(b * NL + 1024 + lp)) * NH + h) * ND + d0;
    *(f32x4*)op = r;
}

// ---- fallback (ws only fits Kbf+Vt): single kernel, full chunk ranges ----
__global__ __launch_bounds__(256)
void fa_single(const float* __restrict__ Q, const float* __restrict__ Bias,
               float* __restrict__ Ws, float* __restrict__ Out)
{
    __shared__ __bf16 Klin[2][4096];
    __shared__ __bf16 Vlin[2][4096];
    const int id = blockIdx.x;
    const int bh = id & 31, qc = 31 - (id >> 5);
    const int b  = bh >> 3, h = bh & 7;
    const u16* Kbf = (const u16*)(Ws + KBF_F);
    const u16* Vt  = (const u16*)(Ws + VT_F);
    fa_core<false>(Q, Kbf, Vt, Bias, Out, nullptr, nullptr, b, h, qc << 6, 0, qc + 1, Klin, Vlin);
}

extern "C" void kernel_launch(void* const* d_in, const int* in_sizes, int n_in,
                              void* d_out, int out_size, void* d_ws, size_t ws_size,
                              hipStream_t stream)
{
    const float* Q    = (const float*)d_in[0];
    const float* K    = (const float*)d_in[1];
    const float* V    = (const float*)d_in[2];
    const float* Bias = (const float*)d_in[3];
    float* Out = (float*)d_out;
    float* Ws  = (float*)d_ws;

    // fused pre-pass: K -> bf16 (same layout) + V -> bf16 transposed [b][h][d][s]
    prep<<<dim3(3072), dim3(256), 0, stream>>>(K, V, (u16*)(Ws + KBF_F), (u16*)(Ws + VT_F));

    if (ws_size >= (size_t)WS_NEED_F * sizeof(float)) {
        fa_part <<<dim3(1536), dim3(256), 0, stream>>>(Q, Bias, Ws, Out);
        fa_merge<<<dim3(2048), dim3(256), 0, stream>>>(Ws, Out);
    } else {
        fa_single<<<dim3(1024), dim3(256), 0, stream>>>(Q, Bias, Ws, Out);
    }
}